// Round 6
// baseline (1395.015 us; speedup 1.0000x reference)
//
#include <hip/hip_runtime.h>
#include <stdint.h>

#define RES 512
#define RANK 48
#define OUT_CH 32
#define KBITS 5
#define NBKT (1 << (3 * KBITS))   // 32768 buckets
#define STR 24                    // compact: 24 u32 (48 bf16) per texel = 96 B

typedef unsigned int u32;
typedef unsigned short u16;
typedef u32 u32x4 __attribute__((ext_vector_type(4)));

// ---------- helpers ----------

static __device__ __forceinline__ u16 f2bf(float f){
  u32 u = __float_as_uint(f);
  u32 r = (u + 0x7fffu + ((u >> 16) & 1u)) >> 16;   // RNE, inputs finite
  return (u16)r;
}

struct PS { int off; float w00, w01, w10, w11; };
static __device__ __forceinline__ PS plane_setup(float gx, float gy){
  float fx = (gx + 1.f) * 255.5f;       // (g+1)*0.5*(RES-1)
  float fy = (gy + 1.f) * 255.5f;
  float x0f = fminf(fmaxf(floorf(fx), 0.f), 510.f);
  float y0f = fminf(fmaxf(floorf(fy), 0.f), 510.f);
  float wx = fx - x0f, wy = fy - y0f;
  PS s;
  s.off = (int)y0f * RES + (int)x0f;
  float ux = 1.f - wx, uy = 1.f - wy;
  s.w00 = uy * ux; s.w01 = uy * wx; s.w10 = wy * ux; s.w11 = wy * wx;
  return s;
}

struct LS { int off; float w; };
static __device__ __forceinline__ LS line_setup(float g){
  float f = (g + 1.f) * 255.5f;
  float i0f = fminf(fmaxf(floorf(f), 0.f), 510.f);
  LS s; s.off = (int)i0f; s.w = f - i0f;
  return s;
}

static __device__ __forceinline__ void contract(const float* __restrict__ aabb,
                                                float px, float py, float pz,
                                                float& cx, float& cy, float& cz){
  float c0 = (aabb[0] + aabb[3]) * 0.5f;
  float c1 = (aabb[1] + aabb[4]) * 0.5f;
  float c2 = (aabb[2] + aabb[5]) * 0.5f;
  float h0 = fmaxf((aabb[3] - aabb[0]) * 0.5f, 1e-6f);
  float h1 = fmaxf((aabb[4] - aabb[1]) * 0.5f, 1e-6f);
  float h2 = fmaxf((aabb[5] - aabb[2]) * 0.5f, 1e-6f);
  float x0 = (px - c0) / h0;
  float x1 = (py - c1) / h1;
  float x2 = (pz - c2) / h2;
  float linf = fmaxf(fabsf(x0), fmaxf(fabsf(x1), fabsf(x2)));
  float scale = 1.f;
  if (linf > 1.f){ float inv = 1.f / linf; scale = (2.f - inv) * inv; }
  cx = fminf(fmaxf(x0 * scale, -1.f), 1.f);
  cy = fminf(fmaxf(x1 * scale, -1.f), 1.f);
  cz = fminf(fmaxf(x2 * scale, -1.f), 1.f);
}

static __device__ __forceinline__ u32 spread3(u32 x){
  x &= 0x3FF;
  x = (x | (x << 16)) & 0x030000FF;
  x = (x | (x <<  8)) & 0x0300F00F;
  x = (x | (x <<  4)) & 0x030C30C3;
  x = (x | (x <<  2)) & 0x09249249;
  return x;
}

static __device__ __forceinline__ u32 morton_key(float cx, float cy, float cz){
  u32 kx = (u32)fminf(fmaxf((cx + 1.f) * 16.f, 0.f), 31.f);
  u32 ky = (u32)fminf(fmaxf((cy + 1.f) * 16.f, 0.f), 31.f);
  u32 kz = (u32)fminf(fmaxf((cz + 1.f) * 16.f, 0.f), 31.f);
  return spread3(kx) | (spread3(ky) << 1) | (spread3(kz) << 2);   // 15 bits
}

// ---------- zero hist (replaces graph memset node) ----------

__global__ void zero_hist(u32* __restrict__ hist)
{
  hist[blockIdx.x * 1024 + threadIdx.x] = 0u;
}

// ---------- fused prep: transpose planes+lines AND histogram keys ----------

#define TRANS_P 3072
#define TRANS_L 6

__global__ void prep_fused(const float* __restrict__ pxy, const float* __restrict__ pxz,
                           const float* __restrict__ pyz,
                           const float* __restrict__ lz, const float* __restrict__ ly,
                           const float* __restrict__ lx,
                           const float* __restrict__ coords, const float* __restrict__ aabb,
                           u32* __restrict__ dstP, u32* __restrict__ dstL,
                           u32* __restrict__ hist, int n)
{
  __shared__ u32 lds[256 * 25];
  int bid = blockIdx.x;
  int tid = threadIdx.x;
  if (bid < TRANS_P){
    int xh = bid & 1, y = (bid >> 1) & 511, p = bid >> 10;
    const float* src = (p == 0) ? pxy : (p == 1) ? pxz : pyz;
    int x = xh * 256 + tid;
    #pragma unroll
    for (int r2 = 0; r2 < 24; ++r2){
      float f0 = src[((size_t)(2 * r2) * RES + y) * RES + x];
      float f1 = src[((size_t)(2 * r2 + 1) * RES + y) * RES + x];
      lds[tid * 25 + r2] = (u32)f2bf(f0) | ((u32)f2bf(f1) << 16);
    }
    __syncthreads();
    u32* dplane = dstP + (size_t)p * (RES * RES * STR);
    size_t base = ((size_t)y * RES + xh * 256) * STR;
    for (int t = tid; t < 256 * STR; t += 256){
      dplane[base + t] = lds[t + t / 24];   // [x][r] read with +1 pad, linear write
    }
  } else if (bid < TRANS_P + TRANS_L){
    int g = (bid - TRANS_P) * 256 + tid;
    if (g < 3 * RES){
      int p = g >> 9, i = g & 511;
      const float* src = (p == 0) ? lz : (p == 1) ? ly : lx;
      u32* d = dstL + (size_t)g * STR;
      #pragma unroll
      for (int r2 = 0; r2 < 24; ++r2){
        float f0 = src[(2 * r2) * RES + i];
        float f1 = src[(2 * r2 + 1) * RES + i];
        d[r2] = (u32)f2bf(f0) | ((u32)f2bf(f1) << 16);
      }
    }
  } else {
    int i = (bid - TRANS_P - TRANS_L) * 256 + tid;
    if (i < n){
      float cx, cy, cz;
      contract(aabb, coords[3*i], coords[3*i+1], coords[3*i+2], cx, cy, cz);
      atomicAdd(hist + morton_key(cx, cy, cz), 1u);
    }
  }
}

// ---------- scan: 32768 buckets, one block ----------

__global__ void scan_kernel(u32* __restrict__ hist)
{
  __shared__ u32 part[1024];
  int tid = threadIdx.x;
  int base = tid * 32;
  u32 loc[32];
  u32 s = 0;
  #pragma unroll
  for (int j = 0; j < 32; j++){ loc[j] = hist[base + j]; s += loc[j]; }
  part[tid] = s;
  __syncthreads();
  for (int off = 1; off < 1024; off <<= 1){
    u32 v = 0;
    if (tid >= off) v = part[tid - off];
    __syncthreads();
    part[tid] += v;
    __syncthreads();
  }
  u32 run = part[tid] - s;
  #pragma unroll
  for (int j = 0; j < 32; j++){ u32 t = loc[j]; hist[base + j] = run; run += t; }
}

__global__ void key_scatter(const float* __restrict__ coords, const float* __restrict__ aabb,
                            u32* __restrict__ hist, float4* __restrict__ sorted, int n)
{
  int i = blockIdx.x * 256 + threadIdx.x;
  if (i >= n) return;
  float cx, cy, cz;
  contract(aabb, coords[3*i], coords[3*i+1], coords[3*i+2], cx, cy, cz);
  u32 pos = atomicAdd(hist + morton_key(cx, cy, cz), 1u);
  sorted[pos] = make_float4(cx, cy, cz, __uint_as_float((u32)i));
}

// ---------- core per-point compute with wave-uniform zero-weight skip ----------

#define EXLO(u) __uint_as_float((u) << 16)
#define EXHI(u) __uint_as_float((u) & 0xffff0000u)

#define DO_ELEM(EX, RIDX) do{ \
  float pa = fmaf(EX(a00[jj]), sa.w00, fmaf(EX(a01[jj]), sa.w01, fmaf(EX(a10[jj]), sa.w10, EX(a11[jj]) * sa.w11))); \
  float pb = fmaf(EX(b00[jj]), sb.w00, fmaf(EX(b01[jj]), sb.w01, fmaf(EX(b10[jj]), sb.w10, EX(b11[jj]) * sb.w11))); \
  float pc = fmaf(EX(c00[jj]), sc.w00, fmaf(EX(c01[jj]), sc.w01, fmaf(EX(c10[jj]), sc.w10, EX(c11[jj]) * sc.w11))); \
  float lzv = fmaf(tz.w, EX(vz1[jj]) - EX(vz0[jj]), EX(vz0[jj])); \
  float lyv = fmaf(ty.w, EX(vy1[jj]) - EX(vy0[jj]), EX(vy0[jj])); \
  float lxv = fmaf(tx.w, EX(vx1[jj]) - EX(vx0[jj]), EX(vx0[jj])); \
  float vm = fmaf(pa, lzv, fmaf(pb, lyv, pc * lxv)); \
  const float4* wrow = Wt4 + (RIDX) * 8; \
  _Pragma("unroll") for (int q = 0; q < 8; q++){ float4 w4 = wrow[q]; \
    acc[4*q+0] = fmaf(vm, w4.x, acc[4*q+0]); acc[4*q+1] = fmaf(vm, w4.y, acc[4*q+1]); \
    acc[4*q+2] = fmaf(vm, w4.z, acc[4*q+2]); acc[4*q+3] = fmaf(vm, w4.w, acc[4*q+3]); } \
}while(0)

// conditional 16B load, condition is wave-uniform in the common (sorted) case
#define CLOAD(dst, cond, ptr) u32x4 dst = {0,0,0,0}; if (cond) dst = *(const u32x4*)(ptr)

static __device__ __forceinline__ void geo_compute(float cx, float cy, float cz,
    const u32* __restrict__ pl, const u32* __restrict__ ln,
    const float* __restrict__ Wt, const float* __restrict__ bias,
    float* __restrict__ acc)
{
  PS sa = plane_setup(cx, cy);   // plane_xy * line_z
  PS sb = plane_setup(cx, cz);   // plane_xz * line_y
  PS sc = plane_setup(cy, cz);   // plane_yz * line_x
  LS tz = line_setup(cz);
  LS ty = line_setup(cy);
  LS tx = line_setup(cx);

  // ~88% of points are exactly on a cube face (contract clips the dominant
  // axis) -> one plane weight row/col and one line tap are exactly 0 for a
  // whole sorted wave. Vote once, skip those loads (vmem-issue-bound kernel).
  bool aY0 = !__all(sa.w00 + sa.w01 == 0.f), aY1 = !__all(sa.w10 + sa.w11 == 0.f);
  bool aX0 = !__all(sa.w00 + sa.w10 == 0.f), aX1 = !__all(sa.w01 + sa.w11 == 0.f);
  bool bY0 = !__all(sb.w00 + sb.w01 == 0.f), bY1 = !__all(sb.w10 + sb.w11 == 0.f);
  bool bX0 = !__all(sb.w00 + sb.w10 == 0.f), bX1 = !__all(sb.w01 + sb.w11 == 0.f);
  bool cY0 = !__all(sc.w00 + sc.w01 == 0.f), cY1 = !__all(sc.w10 + sc.w11 == 0.f);
  bool cX0 = !__all(sc.w00 + sc.w10 == 0.f), cX1 = !__all(sc.w01 + sc.w11 == 0.f);
  bool ld_a00 = aY0 && aX0, ld_a01 = aY0 && aX1, ld_a10 = aY1 && aX0, ld_a11 = aY1 && aX1;
  bool ld_b00 = bY0 && bX0, ld_b01 = bY0 && bX1, ld_b10 = bY1 && bX0, ld_b11 = bY1 && bX1;
  bool ld_c00 = cY0 && cX0, ld_c01 = cY0 && cX1, ld_c10 = cY1 && cX0, ld_c11 = cY1 && cX1;
  bool ld_z0 = !__all(tz.w == 1.f), ld_z1 = !__all(tz.w == 0.f);
  bool ld_y0 = !__all(ty.w == 1.f), ld_y1 = !__all(ty.w == 0.f);
  bool ld_x0 = !__all(tx.w == 1.f), ld_x1 = !__all(tx.w == 0.f);

  const u32* P0 = pl + (size_t)sa.off * STR;
  const u32* P1 = pl + (size_t)RES * RES * STR     + (size_t)sb.off * STR;
  const u32* P2 = pl + (size_t)2 * RES * RES * STR + (size_t)sc.off * STR;
  const u32* LZp = ln +                          (size_t)tz.off * STR;
  const u32* LYp = ln + (size_t)RES * STR     + (size_t)ty.off * STR;
  const u32* LXp = ln + (size_t)2 * RES * STR + (size_t)tx.off * STR;

  #pragma unroll
  for (int o = 0; o < 8; o++){
    float4 bv = *(const float4*)(bias + o * 4);
    acc[4*o+0] = bv.x; acc[4*o+1] = bv.y; acc[4*o+2] = bv.z; acc[4*o+3] = bv.w;
  }
  const float4* Wt4 = (const float4*)Wt;

  #pragma unroll 2
  for (int ch = 0; ch < 6; ++ch){
    const int bo = ch * 4;
    CLOAD(a00, ld_a00, P0 + bo);
    CLOAD(a01, ld_a01, P0 + STR + bo);
    CLOAD(a10, ld_a10, P0 + RES * STR + bo);
    CLOAD(a11, ld_a11, P0 + RES * STR + STR + bo);
    CLOAD(b00, ld_b00, P1 + bo);
    CLOAD(b01, ld_b01, P1 + STR + bo);
    CLOAD(b10, ld_b10, P1 + RES * STR + bo);
    CLOAD(b11, ld_b11, P1 + RES * STR + STR + bo);
    CLOAD(c00, ld_c00, P2 + bo);
    CLOAD(c01, ld_c01, P2 + STR + bo);
    CLOAD(c10, ld_c10, P2 + RES * STR + bo);
    CLOAD(c11, ld_c11, P2 + RES * STR + STR + bo);
    CLOAD(vz0, ld_z0, LZp + bo);
    CLOAD(vz1, ld_z1, LZp + STR + bo);
    CLOAD(vy0, ld_y0, LYp + bo);
    CLOAD(vy1, ld_y1, LYp + STR + bo);
    CLOAD(vx0, ld_x0, LXp + bo);
    CLOAD(vx1, ld_x1, LXp + STR + bo);

    #pragma unroll
    for (int jj = 0; jj < 4; jj++){
      DO_ELEM(EXLO, ch * 8 + jj * 2);
      DO_ELEM(EXHI, ch * 8 + jj * 2 + 1);
    }
  }
}

// ---------- main kernel (sorted path) ----------

__global__ __launch_bounds__(256, 2)
void geo_sorted(const float4* __restrict__ sorted,
                const u32* __restrict__ pl, const u32* __restrict__ ln,
                const float* __restrict__ W, const float* __restrict__ bias,
                float* __restrict__ out, int n, int nwg)
{
  __shared__ __align__(16) float Wt[RANK * OUT_CH];   // Wt[r*32+o]
  for (int t = threadIdx.x; t < RANK * OUT_CH; t += 256){
    int r = t >> 5, o = t & 31;
    Wt[t] = W[o * RANK + r];
  }
  __syncthreads();

  // bijective XCD-chunk swizzle (m204)
  int bid = blockIdx.x;
  int q = nwg >> 3, r8 = nwg & 7;
  int xcd = bid & 7, sub = bid >> 3;
  int swz = (xcd < r8 ? xcd * (q + 1) : r8 * (q + 1) + (xcd - r8) * q) + sub;

  int i = swz * 256 + threadIdx.x;
  if (i >= n) return;

  u32x4 pr = __builtin_nontemporal_load((const u32x4*)(sorted + i));
  float cx = __uint_as_float(pr[0]);
  float cy = __uint_as_float(pr[1]);
  float cz = __uint_as_float(pr[2]);
  u32 oidx = pr[3];

  float acc[OUT_CH];
  geo_compute(cx, cy, cz, pl, ln, Wt, bias, acc);

  float4* o4 = (float4*)(out + (size_t)oidx * 32);
  #pragma unroll
  for (int qq = 0; qq < 8; qq++)
    o4[qq] = make_float4(acc[4*qq+0], acc[4*qq+1], acc[4*qq+2], acc[4*qq+3]);
}

// ---------- mid path (transposed, unsorted) ----------

__global__ __launch_bounds__(256, 2)
void geo_unsorted(const float* __restrict__ coords, const float* __restrict__ aabb,
                  const u32* __restrict__ pl, const u32* __restrict__ ln,
                  const float* __restrict__ W, const float* __restrict__ bias,
                  float* __restrict__ out, int n)
{
  __shared__ __align__(16) float Wt[RANK * OUT_CH];
  for (int t = threadIdx.x; t < RANK * OUT_CH; t += 256){
    int r = t >> 5, o = t & 31;
    Wt[t] = W[o * RANK + r];
  }
  __syncthreads();

  int i = blockIdx.x * 256 + threadIdx.x;
  if (i >= n) return;

  float cx, cy, cz;
  contract(aabb, coords[3*i], coords[3*i+1], coords[3*i+2], cx, cy, cz);

  float acc[OUT_CH];
  geo_compute(cx, cy, cz, pl, ln, Wt, bias, acc);

  float4* o4 = (float4*)(out + (size_t)i * 32);
  #pragma unroll
  for (int qq = 0; qq < 8; qq++)
    o4[qq] = make_float4(acc[4*qq+0], acc[4*qq+1], acc[4*qq+2], acc[4*qq+3]);
}

// ---------- fallback (ws too small): direct sampling from original layout ----------

__global__ __launch_bounds__(256, 2)
void geo_direct(const float* __restrict__ coords, const float* __restrict__ aabb,
                const float* __restrict__ PXY, const float* __restrict__ PXZ, const float* __restrict__ PYZ,
                const float* __restrict__ LZ, const float* __restrict__ LY, const float* __restrict__ LX,
                const float* __restrict__ W, const float* __restrict__ bias,
                float* __restrict__ out, int n)
{
  __shared__ __align__(16) float Wt[RANK * OUT_CH];
  for (int t = threadIdx.x; t < RANK * OUT_CH; t += 256){
    int r = t >> 5, o = t & 31;
    Wt[t] = W[o * RANK + r];
  }
  __syncthreads();

  int i = blockIdx.x * 256 + threadIdx.x;
  if (i >= n) return;

  float cx, cy, cz;
  contract(aabb, coords[3*i], coords[3*i+1], coords[3*i+2], cx, cy, cz);

  PS sa = plane_setup(cx, cy);
  PS sb = plane_setup(cx, cz);
  PS sc = plane_setup(cy, cz);
  LS tz = line_setup(cz);
  LS ty = line_setup(cy);
  LS tx = line_setup(cx);

  float acc[OUT_CH];
  #pragma unroll
  for (int o = 0; o < 8; o++){
    float4 bv = *(const float4*)(bias + o * 4);
    acc[4*o+0] = bv.x; acc[4*o+1] = bv.y; acc[4*o+2] = bv.z; acc[4*o+3] = bv.w;
  }
  const float4* Wt4 = (const float4*)Wt;

  for (int r = 0; r < RANK; r++){
    const float* pA = PXY + (size_t)r * RES * RES;
    const float* pB = PXZ + (size_t)r * RES * RES;
    const float* pC = PYZ + (size_t)r * RES * RES;
    float va = fmaf(pA[sa.off], sa.w00, fmaf(pA[sa.off+1], sa.w01, fmaf(pA[sa.off+RES], sa.w10, pA[sa.off+RES+1]*sa.w11)));
    float vb = fmaf(pB[sb.off], sb.w00, fmaf(pB[sb.off+1], sb.w01, fmaf(pB[sb.off+RES], sb.w10, pB[sb.off+RES+1]*sb.w11)));
    float vc = fmaf(pC[sc.off], sc.w00, fmaf(pC[sc.off+1], sc.w01, fmaf(pC[sc.off+RES], sc.w10, pC[sc.off+RES+1]*sc.w11)));
    float l0;
    l0 = LZ[r * RES + tz.off];
    float lzv = fmaf(tz.w, LZ[r * RES + tz.off + 1] - l0, l0);
    l0 = LY[r * RES + ty.off];
    float lyv = fmaf(ty.w, LY[r * RES + ty.off + 1] - l0, l0);
    l0 = LX[r * RES + tx.off];
    float lxv = fmaf(tx.w, LX[r * RES + tx.off + 1] - l0, l0);
    float vm = fmaf(va, lzv, fmaf(vb, lyv, vc * lxv));
    const float4* wrow = Wt4 + r * 8;
    #pragma unroll
    for (int q = 0; q < 8; q++){
      float4 w4 = wrow[q];
      acc[4*q+0] = fmaf(vm, w4.x, acc[4*q+0]); acc[4*q+1] = fmaf(vm, w4.y, acc[4*q+1]);
      acc[4*q+2] = fmaf(vm, w4.z, acc[4*q+2]); acc[4*q+3] = fmaf(vm, w4.w, acc[4*q+3]);
    }
  }

  float4* o4 = (float4*)(out + (size_t)i * 32);
  #pragma unroll
  for (int q = 0; q < 8; q++)
    o4[q] = make_float4(acc[4*q+0], acc[4*q+1], acc[4*q+2], acc[4*q+3]);
}

// ---------- launch ----------

extern "C" void kernel_launch(void* const* d_in, const int* in_sizes, int n_in,
                              void* d_out, int out_size, void* d_ws, size_t ws_size,
                              hipStream_t stream)
{
  const float* coords = (const float*)d_in[0];
  const float* aabb   = (const float*)d_in[1];
  const float* pxy    = (const float*)d_in[2];
  const float* pxz    = (const float*)d_in[3];
  const float* pyz    = (const float*)d_in[4];
  const float* lz     = (const float*)d_in[5];
  const float* ly     = (const float*)d_in[6];
  const float* lx     = (const float*)d_in[7];
  const float* W      = (const float*)d_in[8];
  const float* bias   = (const float*)d_in[9];
  float* out = (float*)d_out;
  int n = in_sizes[0] / 3;
  int nwg = (n + 255) / 256;

  const size_t planesU = (size_t)3 * RES * RES * STR;
  const size_t linesU  = (size_t)3 * RES * STR;
  const size_t histU   = NBKT;
  const size_t sortedU = (size_t)4 * n;
  const size_t needFull = (planesU + linesU + histU + sortedU) * 4;   // ~92 MB

  if (ws_size >= needFull){
    u32* pl   = (u32*)d_ws;
    u32* ln   = pl + planesU;
    u32* hist = ln + linesU;
    float4* sorted = (float4*)(hist + histU);
    zero_hist<<<NBKT / 1024, 1024, 0, stream>>>(hist);
    prep_fused<<<TRANS_P + TRANS_L + nwg, 256, 0, stream>>>(
        pxy, pxz, pyz, lz, ly, lx, coords, aabb, pl, ln, hist, n);
    scan_kernel<<<1, 1024, 0, stream>>>(hist);
    key_scatter<<<nwg, 256, 0, stream>>>(coords, aabb, hist, sorted, n);
    geo_sorted<<<nwg, 256, 0, stream>>>(sorted, pl, ln, W, bias, out, n, nwg);
  } else if (ws_size >= (planesU + linesU) * 4){
    u32* pl = (u32*)d_ws;
    u32* ln = pl + planesU;
    prep_fused<<<TRANS_P + TRANS_L, 256, 0, stream>>>(
        pxy, pxz, pyz, lz, ly, lx, coords, aabb, pl, ln, (u32*)pl, 0);
    geo_unsorted<<<nwg, 256, 0, stream>>>(coords, aabb, pl, ln, W, bias, out, n);
  } else {
    geo_direct<<<nwg, 256, 0, stream>>>(coords, aabb, pxy, pxz, pyz, lz, ly, lx, W, bias, out, n);
  }
}

// Round 7
// 413.834 us; speedup vs baseline: 3.3710x; 3.3710x over previous
//
#include <hip/hip_runtime.h>
#include <stdint.h>

#define RES 512
#define RANK 48
#define OUT_CH 32
#define KBITS 5
#define NBKT (1 << (3 * KBITS))   // 32768 buckets
#define STR 24                    // compact: 24 u32 (48 bf16) per texel = 96 B

typedef unsigned int u32;
typedef unsigned short u16;
typedef u32 u32x4 __attribute__((ext_vector_type(4)));

// ---------- helpers ----------

static __device__ __forceinline__ u16 f2bf(float f){
  u32 u = __float_as_uint(f);
  u32 r = (u + 0x7fffu + ((u >> 16) & 1u)) >> 16;   // RNE, inputs finite
  return (u16)r;
}

struct PS { int off; float w00, w01, w10, w11; };
static __device__ __forceinline__ PS plane_setup(float gx, float gy){
  float fx = (gx + 1.f) * 255.5f;       // (g+1)*0.5*(RES-1)
  float fy = (gy + 1.f) * 255.5f;
  float x0f = fminf(fmaxf(floorf(fx), 0.f), 510.f);
  float y0f = fminf(fmaxf(floorf(fy), 0.f), 510.f);
  float wx = fx - x0f, wy = fy - y0f;
  PS s;
  s.off = (int)y0f * RES + (int)x0f;
  float ux = 1.f - wx, uy = 1.f - wy;
  s.w00 = uy * ux; s.w01 = uy * wx; s.w10 = wy * ux; s.w11 = wy * wx;
  return s;
}

struct LS { int off; float w; };
static __device__ __forceinline__ LS line_setup(float g){
  float f = (g + 1.f) * 255.5f;
  float i0f = fminf(fmaxf(floorf(f), 0.f), 510.f);
  LS s; s.off = (int)i0f; s.w = f - i0f;
  return s;
}

static __device__ __forceinline__ void contract(const float* __restrict__ aabb,
                                                float px, float py, float pz,
                                                float& cx, float& cy, float& cz){
  float c0 = (aabb[0] + aabb[3]) * 0.5f;
  float c1 = (aabb[1] + aabb[4]) * 0.5f;
  float c2 = (aabb[2] + aabb[5]) * 0.5f;
  float h0 = fmaxf((aabb[3] - aabb[0]) * 0.5f, 1e-6f);
  float h1 = fmaxf((aabb[4] - aabb[1]) * 0.5f, 1e-6f);
  float h2 = fmaxf((aabb[5] - aabb[2]) * 0.5f, 1e-6f);
  float x0 = (px - c0) / h0;
  float x1 = (py - c1) / h1;
  float x2 = (pz - c2) / h2;
  float linf = fmaxf(fabsf(x0), fmaxf(fabsf(x1), fabsf(x2)));
  float scale = 1.f;
  if (linf > 1.f){ float inv = 1.f / linf; scale = (2.f - inv) * inv; }
  cx = fminf(fmaxf(x0 * scale, -1.f), 1.f);
  cy = fminf(fmaxf(x1 * scale, -1.f), 1.f);
  cz = fminf(fmaxf(x2 * scale, -1.f), 1.f);
}

static __device__ __forceinline__ u32 spread3(u32 x){
  x &= 0x3FF;
  x = (x | (x << 16)) & 0x030000FF;
  x = (x | (x <<  8)) & 0x0300F00F;
  x = (x | (x <<  4)) & 0x030C30C3;
  x = (x | (x <<  2)) & 0x09249249;
  return x;
}

static __device__ __forceinline__ u32 morton_key(float cx, float cy, float cz){
  u32 kx = (u32)fminf(fmaxf((cx + 1.f) * 16.f, 0.f), 31.f);
  u32 ky = (u32)fminf(fmaxf((cy + 1.f) * 16.f, 0.f), 31.f);
  u32 kz = (u32)fminf(fmaxf((cz + 1.f) * 16.f, 0.f), 31.f);
  return spread3(kx) | (spread3(ky) << 1) | (spread3(kz) << 2);   // 15 bits
}

// ---------- zero hist ----------

__global__ void zero_hist(u32* __restrict__ hist)
{
  hist[blockIdx.x * 1024 + threadIdx.x] = 0u;
}

// ---------- fused prep: transpose planes+lines AND hist+keyrank ----------
// hist pass also records keyrank[i] = (rank<<15)|key so the scatter pass
// needs NO atomics (pos = scanned_base[key] + rank).

#define TRANS_P 3072
#define TRANS_L 6

__global__ void prep_fused(const float* __restrict__ pxy, const float* __restrict__ pxz,
                           const float* __restrict__ pyz,
                           const float* __restrict__ lz, const float* __restrict__ ly,
                           const float* __restrict__ lx,
                           const float* __restrict__ coords, const float* __restrict__ aabb,
                           u32* __restrict__ dstP, u32* __restrict__ dstL,
                           u32* __restrict__ hist, u32* __restrict__ keyrank, int n)
{
  __shared__ u32 lds[256 * 25];
  int bid = blockIdx.x;
  int tid = threadIdx.x;
  if (bid < TRANS_P){
    int xh = bid & 1, y = (bid >> 1) & 511, p = bid >> 10;
    const float* src = (p == 0) ? pxy : (p == 1) ? pxz : pyz;
    int x = xh * 256 + tid;
    #pragma unroll
    for (int r2 = 0; r2 < 24; ++r2){
      float f0 = src[((size_t)(2 * r2) * RES + y) * RES + x];
      float f1 = src[((size_t)(2 * r2 + 1) * RES + y) * RES + x];
      lds[tid * 25 + r2] = (u32)f2bf(f0) | ((u32)f2bf(f1) << 16);
    }
    __syncthreads();
    u32* dplane = dstP + (size_t)p * (RES * RES * STR);
    size_t base = ((size_t)y * RES + xh * 256) * STR;
    for (int t = tid; t < 256 * STR; t += 256){
      dplane[base + t] = lds[t + t / 24];   // [x][r] read with +1 pad, linear write
    }
  } else if (bid < TRANS_P + TRANS_L){
    int g = (bid - TRANS_P) * 256 + tid;
    if (g < 3 * RES){
      int p = g >> 9, i = g & 511;
      const float* src = (p == 0) ? lz : (p == 1) ? ly : lx;
      u32* d = dstL + (size_t)g * STR;
      #pragma unroll
      for (int r2 = 0; r2 < 24; ++r2){
        float f0 = src[(2 * r2) * RES + i];
        float f1 = src[(2 * r2 + 1) * RES + i];
        d[r2] = (u32)f2bf(f0) | ((u32)f2bf(f1) << 16);
      }
    }
  } else {
    int i = (bid - TRANS_P - TRANS_L) * 256 + tid;
    if (i < n){
      float cx, cy, cz;
      contract(aabb, coords[3*i], coords[3*i+1], coords[3*i+2], cx, cy, cz);
      u32 key = morton_key(cx, cy, cz);
      u32 rank = atomicAdd(hist + key, 1u);
      keyrank[i] = (rank << 15) | key;   // rank < 2^17 (avg ~30/bucket)
    }
  }
}

// ---------- scan: 32768 buckets, one block ----------

__global__ void scan_kernel(u32* __restrict__ hist)
{
  __shared__ u32 part[1024];
  int tid = threadIdx.x;
  int base = tid * 32;
  u32 loc[32];
  u32 s = 0;
  #pragma unroll
  for (int j = 0; j < 32; j++){ loc[j] = hist[base + j]; s += loc[j]; }
  part[tid] = s;
  __syncthreads();
  for (int off = 1; off < 1024; off <<= 1){
    u32 v = 0;
    if (tid >= off) v = part[tid - off];
    __syncthreads();
    part[tid] += v;
    __syncthreads();
  }
  u32 run = part[tid] - s;
  #pragma unroll
  for (int j = 0; j < 32; j++){ u32 t = loc[j]; hist[base + j] = run; run += t; }
}

// ---------- scatter: NO atomics (base[key] + rank) ----------

__global__ void key_scatter(const float* __restrict__ coords, const float* __restrict__ aabb,
                            const u32* __restrict__ base, const u32* __restrict__ keyrank,
                            float4* __restrict__ sorted, int n)
{
  int i = blockIdx.x * 256 + threadIdx.x;
  if (i >= n) return;
  float cx, cy, cz;
  contract(aabb, coords[3*i], coords[3*i+1], coords[3*i+2], cx, cy, cz);
  u32 kr = keyrank[i];
  u32 pos = base[kr & 0x7FFFu] + (kr >> 15);
  sorted[pos] = make_float4(cx, cy, cz, __uint_as_float((u32)i));
}

// ---------- core per-point compute (R3-exact: unconditional loads) ----------

#define EXLO(u) __uint_as_float((u) << 16)
#define EXHI(u) __uint_as_float((u) & 0xffff0000u)

#define DO_ELEM(EX, RIDX) do{ \
  float pa = fmaf(EX(a00[jj]), sa.w00, fmaf(EX(a01[jj]), sa.w01, fmaf(EX(a10[jj]), sa.w10, EX(a11[jj]) * sa.w11))); \
  float pb = fmaf(EX(b00[jj]), sb.w00, fmaf(EX(b01[jj]), sb.w01, fmaf(EX(b10[jj]), sb.w10, EX(b11[jj]) * sb.w11))); \
  float pc = fmaf(EX(c00[jj]), sc.w00, fmaf(EX(c01[jj]), sc.w01, fmaf(EX(c10[jj]), sc.w10, EX(c11[jj]) * sc.w11))); \
  float lzv = fmaf(tz.w, EX(vz1[jj]) - EX(vz0[jj]), EX(vz0[jj])); \
  float lyv = fmaf(ty.w, EX(vy1[jj]) - EX(vy0[jj]), EX(vy0[jj])); \
  float lxv = fmaf(tx.w, EX(vx1[jj]) - EX(vx0[jj]), EX(vx0[jj])); \
  float vm = fmaf(pa, lzv, fmaf(pb, lyv, pc * lxv)); \
  const float4* wrow = Wt4 + (RIDX) * 8; \
  _Pragma("unroll") for (int q = 0; q < 8; q++){ float4 w4 = wrow[q]; \
    acc[4*q+0] = fmaf(vm, w4.x, acc[4*q+0]); acc[4*q+1] = fmaf(vm, w4.y, acc[4*q+1]); \
    acc[4*q+2] = fmaf(vm, w4.z, acc[4*q+2]); acc[4*q+3] = fmaf(vm, w4.w, acc[4*q+3]); } \
}while(0)

static __device__ __forceinline__ void geo_compute(float cx, float cy, float cz,
    const u32* __restrict__ pl, const u32* __restrict__ ln,
    const float* __restrict__ Wt, const float* __restrict__ bias,
    float* __restrict__ acc)
{
  PS sa = plane_setup(cx, cy);   // plane_xy * line_z
  PS sb = plane_setup(cx, cz);   // plane_xz * line_y
  PS sc = plane_setup(cy, cz);   // plane_yz * line_x
  LS tz = line_setup(cz);
  LS ty = line_setup(cy);
  LS tx = line_setup(cx);

  const u32* P0 = pl + (size_t)sa.off * STR;
  const u32* P1 = pl + (size_t)RES * RES * STR     + (size_t)sb.off * STR;
  const u32* P2 = pl + (size_t)2 * RES * RES * STR + (size_t)sc.off * STR;
  const u32* LZp = ln +                          (size_t)tz.off * STR;
  const u32* LYp = ln + (size_t)RES * STR     + (size_t)ty.off * STR;
  const u32* LXp = ln + (size_t)2 * RES * STR + (size_t)tx.off * STR;

  #pragma unroll
  for (int o = 0; o < 8; o++){
    float4 bv = *(const float4*)(bias + o * 4);
    acc[4*o+0] = bv.x; acc[4*o+1] = bv.y; acc[4*o+2] = bv.z; acc[4*o+3] = bv.w;
  }
  const float4* Wt4 = (const float4*)Wt;

  #pragma unroll 2
  for (int ch = 0; ch < 6; ++ch){
    const int bo = ch * 4;
    u32x4 a00 = *(const u32x4*)(P0 + bo);
    u32x4 a01 = *(const u32x4*)(P0 + STR + bo);
    u32x4 a10 = *(const u32x4*)(P0 + RES * STR + bo);
    u32x4 a11 = *(const u32x4*)(P0 + RES * STR + STR + bo);
    u32x4 b00 = *(const u32x4*)(P1 + bo);
    u32x4 b01 = *(const u32x4*)(P1 + STR + bo);
    u32x4 b10 = *(const u32x4*)(P1 + RES * STR + bo);
    u32x4 b11 = *(const u32x4*)(P1 + RES * STR + STR + bo);
    u32x4 c00 = *(const u32x4*)(P2 + bo);
    u32x4 c01 = *(const u32x4*)(P2 + STR + bo);
    u32x4 c10 = *(const u32x4*)(P2 + RES * STR + bo);
    u32x4 c11 = *(const u32x4*)(P2 + RES * STR + STR + bo);
    u32x4 vz0 = *(const u32x4*)(LZp + bo);
    u32x4 vz1 = *(const u32x4*)(LZp + STR + bo);
    u32x4 vy0 = *(const u32x4*)(LYp + bo);
    u32x4 vy1 = *(const u32x4*)(LYp + STR + bo);
    u32x4 vx0 = *(const u32x4*)(LXp + bo);
    u32x4 vx1 = *(const u32x4*)(LXp + STR + bo);

    #pragma unroll
    for (int jj = 0; jj < 4; jj++){
      DO_ELEM(EXLO, ch * 8 + jj * 2);
      DO_ELEM(EXHI, ch * 8 + jj * 2 + 1);
    }
  }
}

// ---------- main kernel (sorted path) ----------

__global__ __launch_bounds__(256, 2)
void geo_sorted(const float4* __restrict__ sorted,
                const u32* __restrict__ pl, const u32* __restrict__ ln,
                const float* __restrict__ W, const float* __restrict__ bias,
                float* __restrict__ out, int n, int nwg)
{
  __shared__ __align__(16) float Wt[RANK * OUT_CH];   // Wt[r*32+o]
  for (int t = threadIdx.x; t < RANK * OUT_CH; t += 256){
    int r = t >> 5, o = t & 31;
    Wt[t] = W[o * RANK + r];
  }
  __syncthreads();

  // bijective XCD-chunk swizzle (m204)
  int bid = blockIdx.x;
  int q = nwg >> 3, r8 = nwg & 7;
  int xcd = bid & 7, sub = bid >> 3;
  int swz = (xcd < r8 ? xcd * (q + 1) : r8 * (q + 1) + (xcd - r8) * q) + sub;

  int i = swz * 256 + threadIdx.x;
  if (i >= n) return;

  u32x4 pr = __builtin_nontemporal_load((const u32x4*)(sorted + i));
  float cx = __uint_as_float(pr[0]);
  float cy = __uint_as_float(pr[1]);
  float cz = __uint_as_float(pr[2]);
  u32 oidx = pr[3];

  float acc[OUT_CH];
  geo_compute(cx, cy, cz, pl, ln, Wt, bias, acc);

  float4* o4 = (float4*)(out + (size_t)oidx * 32);
  #pragma unroll
  for (int qq = 0; qq < 8; qq++)
    o4[qq] = make_float4(acc[4*qq+0], acc[4*qq+1], acc[4*qq+2], acc[4*qq+3]);
}

// ---------- mid path (transposed, unsorted) ----------

__global__ __launch_bounds__(256, 2)
void geo_unsorted(const float* __restrict__ coords, const float* __restrict__ aabb,
                  const u32* __restrict__ pl, const u32* __restrict__ ln,
                  const float* __restrict__ W, const float* __restrict__ bias,
                  float* __restrict__ out, int n)
{
  __shared__ __align__(16) float Wt[RANK * OUT_CH];
  for (int t = threadIdx.x; t < RANK * OUT_CH; t += 256){
    int r = t >> 5, o = t & 31;
    Wt[t] = W[o * RANK + r];
  }
  __syncthreads();

  int i = blockIdx.x * 256 + threadIdx.x;
  if (i >= n) return;

  float cx, cy, cz;
  contract(aabb, coords[3*i], coords[3*i+1], coords[3*i+2], cx, cy, cz);

  float acc[OUT_CH];
  geo_compute(cx, cy, cz, pl, ln, Wt, bias, acc);

  float4* o4 = (float4*)(out + (size_t)i * 32);
  #pragma unroll
  for (int qq = 0; qq < 8; qq++)
    o4[qq] = make_float4(acc[4*qq+0], acc[4*qq+1], acc[4*qq+2], acc[4*qq+3]);
}

// ---------- fallback (ws too small): direct sampling from original layout ----------

__global__ __launch_bounds__(256, 2)
void geo_direct(const float* __restrict__ coords, const float* __restrict__ aabb,
                const float* __restrict__ PXY, const float* __restrict__ PXZ, const float* __restrict__ PYZ,
                const float* __restrict__ LZ, const float* __restrict__ LY, const float* __restrict__ LX,
                const float* __restrict__ W, const float* __restrict__ bias,
                float* __restrict__ out, int n)
{
  __shared__ __align__(16) float Wt[RANK * OUT_CH];
  for (int t = threadIdx.x; t < RANK * OUT_CH; t += 256){
    int r = t >> 5, o = t & 31;
    Wt[t] = W[o * RANK + r];
  }
  __syncthreads();

  int i = blockIdx.x * 256 + threadIdx.x;
  if (i >= n) return;

  float cx, cy, cz;
  contract(aabb, coords[3*i], coords[3*i+1], coords[3*i+2], cx, cy, cz);

  PS sa = plane_setup(cx, cy);
  PS sb = plane_setup(cx, cz);
  PS sc = plane_setup(cy, cz);
  LS tz = line_setup(cz);
  LS ty = line_setup(cy);
  LS tx = line_setup(cx);

  float acc[OUT_CH];
  #pragma unroll
  for (int o = 0; o < 8; o++){
    float4 bv = *(const float4*)(bias + o * 4);
    acc[4*o+0] = bv.x; acc[4*o+1] = bv.y; acc[4*o+2] = bv.z; acc[4*o+3] = bv.w;
  }
  const float4* Wt4 = (const float4*)Wt;

  for (int r = 0; r < RANK; r++){
    const float* pA = PXY + (size_t)r * RES * RES;
    const float* pB = PXZ + (size_t)r * RES * RES;
    const float* pC = PYZ + (size_t)r * RES * RES;
    float va = fmaf(pA[sa.off], sa.w00, fmaf(pA[sa.off+1], sa.w01, fmaf(pA[sa.off+RES], sa.w10, pA[sa.off+RES+1]*sa.w11)));
    float vb = fmaf(pB[sb.off], sb.w00, fmaf(pB[sb.off+1], sb.w01, fmaf(pB[sb.off+RES], sb.w10, pB[sb.off+RES+1]*sb.w11)));
    float vc = fmaf(pC[sc.off], sc.w00, fmaf(pC[sc.off+1], sc.w01, fmaf(pC[sc.off+RES], sc.w10, pC[sc.off+RES+1]*sc.w11)));
    float l0;
    l0 = LZ[r * RES + tz.off];
    float lzv = fmaf(tz.w, LZ[r * RES + tz.off + 1] - l0, l0);
    l0 = LY[r * RES + ty.off];
    float lyv = fmaf(ty.w, LY[r * RES + ty.off + 1] - l0, l0);
    l0 = LX[r * RES + tx.off];
    float lxv = fmaf(tx.w, LX[r * RES + tx.off + 1] - l0, l0);
    float vm = fmaf(va, lzv, fmaf(vb, lyv, vc * lxv));
    const float4* wrow = Wt4 + r * 8;
    #pragma unroll
    for (int q = 0; q < 8; q++){
      float4 w4 = wrow[q];
      acc[4*q+0] = fmaf(vm, w4.x, acc[4*q+0]); acc[4*q+1] = fmaf(vm, w4.y, acc[4*q+1]);
      acc[4*q+2] = fmaf(vm, w4.z, acc[4*q+2]); acc[4*q+3] = fmaf(vm, w4.w, acc[4*q+3]);
    }
  }

  float4* o4 = (float4*)(out + (size_t)i * 32);
  #pragma unroll
  for (int q = 0; q < 8; q++)
    o4[q] = make_float4(acc[4*q+0], acc[4*q+1], acc[4*q+2], acc[4*q+3]);
}

// ---------- launch ----------

extern "C" void kernel_launch(void* const* d_in, const int* in_sizes, int n_in,
                              void* d_out, int out_size, void* d_ws, size_t ws_size,
                              hipStream_t stream)
{
  const float* coords = (const float*)d_in[0];
  const float* aabb   = (const float*)d_in[1];
  const float* pxy    = (const float*)d_in[2];
  const float* pxz    = (const float*)d_in[3];
  const float* pyz    = (const float*)d_in[4];
  const float* lz     = (const float*)d_in[5];
  const float* ly     = (const float*)d_in[6];
  const float* lx     = (const float*)d_in[7];
  const float* W      = (const float*)d_in[8];
  const float* bias   = (const float*)d_in[9];
  float* out = (float*)d_out;
  int n = in_sizes[0] / 3;
  int nwg = (n + 255) / 256;

  const size_t planesU = (size_t)3 * RES * RES * STR;
  const size_t linesU  = (size_t)3 * RES * STR;
  const size_t histU   = NBKT;
  const size_t keyrU   = (size_t)n;
  const size_t sortedU = (size_t)4 * n;
  const size_t needFull = (planesU + linesU + histU + keyrU + sortedU) * 4;   // ~96 MB

  if (ws_size >= needFull){
    u32* pl      = (u32*)d_ws;
    u32* ln      = pl + planesU;
    u32* hist    = ln + linesU;
    u32* keyrank = hist + histU;
    float4* sorted = (float4*)(keyrank + keyrU);
    zero_hist<<<NBKT / 1024, 1024, 0, stream>>>(hist);
    prep_fused<<<TRANS_P + TRANS_L + nwg, 256, 0, stream>>>(
        pxy, pxz, pyz, lz, ly, lx, coords, aabb, pl, ln, hist, keyrank, n);
    scan_kernel<<<1, 1024, 0, stream>>>(hist);
    key_scatter<<<nwg, 256, 0, stream>>>(coords, aabb, hist, keyrank, sorted, n);
    geo_sorted<<<nwg, 256, 0, stream>>>(sorted, pl, ln, W, bias, out, n, nwg);
  } else if (ws_size >= (planesU + linesU) * 4){
    u32* pl = (u32*)d_ws;
    u32* ln = pl + planesU;
    prep_fused<<<TRANS_P + TRANS_L, 256, 0, stream>>>(
        pxy, pxz, pyz, lz, ly, lx, coords, aabb, pl, ln, (u32*)pl, (u32*)pl, 0);
    geo_unsorted<<<nwg, 256, 0, stream>>>(coords, aabb, pl, ln, W, bias, out, n);
  } else {
    geo_direct<<<nwg, 256, 0, stream>>>(coords, aabb, pxy, pxz, pyz, lz, ly, lx, W, bias, out, n);
  }
}